// Round 6
// baseline (509.528 us; speedup 1.0000x reference)
//
#include <hip/hip_runtime.h>
#include <cstdint>
#include <cstddef>

#define SEQ 5000
#define CIN 12
#define KL 9
#define ND 10
#define KPD 1000
#define NB 16
#define KPAD 128          // padded taps (108 -> 128)
#define NKP 1024          // padded kernels per dilation (1000 -> 1024)
#define BM 64             // t-points per block
#define NTILES 16         // NKP / 64

typedef __attribute__((ext_vector_type(4))) float f32x4;
typedef __attribute__((ext_vector_type(8))) __bf16 bf16x8;
typedef __attribute__((ext_vector_type(8))) unsigned short u16x8;

__device__ __forceinline__ unsigned fkey(float f) {
    unsigned u = __float_as_uint(f);
    return (u & 0x80000000u) ? ~u : (u | 0x80000000u);
}
__device__ __forceinline__ float unfkey(unsigned k) {
    unsigned u = (k & 0x80000000u) ? (k ^ 0x80000000u) : ~k;
    return __uint_as_float(u);
}
__device__ __forceinline__ unsigned short f2bf(float f) {
    unsigned u = __float_as_uint(f);
    u += 0x7fffu + ((u >> 16) & 1u);
    return (unsigned short)(u >> 16);
}

// ---- weight prep: [10][1000][108] f32 -> [10][1024][128] bf16, zero-padded ----
__global__ __launch_bounds__(256) void wprep(const float* __restrict__ w,
                                             unsigned short* __restrict__ wbf) {
    const int i = blockIdx.x * 256 + threadIdx.x;   // over ND*NKP*KPAD
    if (i >= ND * NKP * KPAD) return;
    const int kk   = i & (KPAD - 1);
    const int krow = (i >> 7) & (NKP - 1);
    const int di   = i >> 17;
    float v = 0.f;
    if (krow < KPD && kk < CIN * KL)
        v = w[((size_t)di * KPD + krow) * (CIN * KL) + kk];
    wbf[i] = f2bf(v);
}

template <bool TAIL>
__device__ __forceinline__ void mr_body(
    const float* __restrict__ xb, const unsigned short* __restrict__ wd,
    const float* __restrict__ bb, unsigned* __restrict__ gkey,
    unsigned* __restrict__ gcnt, int d, int t0,
    unsigned short* lA, size_t slotbase)
{
    const int tid  = threadIdx.x;
    const int lane = tid & 63;
    const int wv   = tid >> 6;

    // ---- gather patch A[64][128] into swizzled LDS (lane = t -> coalesced x reads) ----
    {
        const int row  = tid & 63;
        const int cw   = tid >> 6;           // col group: 32 taps each
        const int base = t0 + row - 4 * d;   // SAME padding: pad_lo = 4d
        int cc = cw * 32;
        int c = cc / 9, j = cc - c * 9;
#pragma unroll
        for (int m = 0; m < 4; ++m) {
            u16x8 pk;
#pragma unroll
            for (int e = 0; e < 8; ++e) {
                const int idx = base + j * d;
                float v = 0.f;
                if ((cc < CIN * KL) && idx >= 0 && idx < SEQ) v = xb[c * SEQ + idx];
                pk[e] = f2bf(v);
                ++cc;
                if (++j == KL) { j = 0; ++c; }
            }
            const int cb   = cw * 64 + m * 16;
            const int addr = row * 256 + (cb ^ ((row & 7) << 4));
            *(u16x8*)((char*)lA + addr) = pk;
        }
    }
    __syncthreads();

    // ---- A fragments -> registers ONCE (16x ds_read_b128, swizzled) ----
    const int fr = lane & 15;   // frag row (t within 16) / frag col (kernel within 16)
    const int ks = lane >> 4;   // k-slice group
    bf16x8 afrag[4][4];
#pragma unroll
    for (int m = 0; m < 4; ++m) {
        const int row = m * 16 + fr;
#pragma unroll
        for (int kk = 0; kk < 4; ++kk) {
            const int cb   = kk * 64 + ks * 16;
            const int addr = row * 256 + (cb ^ ((row & 7) << 4));
            afrag[m][kk] = *(const bf16x8*)((const char*)lA + addr);
        }
    }
    // PIN afrag in VGPRs: opaque asm results cannot be rematerialized/sunk
    // into the k-tile loop (round-5 failure mode: compiler re-read LDS every
    // tile -> 253us of LDS-pipe time vs 102us MFMA floor).
#pragma unroll
    for (int m = 0; m < 4; ++m)
        asm volatile("" : "+v"(afrag[m][0]), "+v"(afrag[m][1]),
                          "+v"(afrag[m][2]), "+v"(afrag[m][3]));

    // per-lane W base: kcol(kt) = kt*64 + wv*16 + fr, k-slice ks*8 within each 32-block
    const unsigned short* wr0 = wd + (size_t)(wv * 16 + fr) * KPAD + ks * 8;

    // prefetch B tile 0
    bf16x8 bfrag[4];
#pragma unroll
    for (int kk = 0; kk < 4; ++kk)
        bfrag[kk] = *(const bf16x8*)(wr0 + kk * 32);

    for (int kt = 0; kt < NTILES; ++kt) {
        // prefetch next tile's B-frags (wraps to 0 on last iter; harmless)
        const int ktn = (kt + 1) & (NTILES - 1);
        const unsigned short* wrn = wr0 + (size_t)ktn * 64 * KPAD;
        bf16x8 bnext[4];
#pragma unroll
        for (int kk = 0; kk < 4; ++kk)
            bnext[kk] = *(const bf16x8*)(wrn + kk * 32);

        f32x4 acc[4];
#pragma unroll
        for (int m = 0; m < 4; ++m) acc[m] = (f32x4){0.f, 0.f, 0.f, 0.f};
#pragma unroll
        for (int m = 0; m < 4; ++m)
#pragma unroll
            for (int kk = 0; kk < 4; ++kk)
                acc[m] = __builtin_amdgcn_mfma_f32_16x16x32_bf16(
                    afrag[m][kk], bfrag[kk], acc[m], 0, 0, 0);

        const int kcol = kt * 64 + wv * 16 + fr;
        const float bv = (kcol < KPD) ? bb[kcol] : 3.0e38f;

        // epilogue in place on acc (no staging array -> low VGPR pressure)
        unsigned pcnt = 0;
        float pm[4];
#pragma unroll
        for (int m = 0; m < 4; ++m) {
            float x0 = acc[m][0], x1 = acc[m][1], x2 = acc[m][2], x3 = acc[m][3];
            if (TAIL) {
                const int tbase = t0 + m * 16 + ks * 4;
                x0 = (tbase + 0 < SEQ) ? x0 : -3.0e38f;
                x1 = (tbase + 1 < SEQ) ? x1 : -3.0e38f;
                x2 = (tbase + 2 < SEQ) ? x2 : -3.0e38f;
                x3 = (tbase + 3 < SEQ) ? x3 : -3.0e38f;
            }
            pcnt += (x0 > bv) ? 1u : 0u;
            pcnt += (x1 > bv) ? 1u : 0u;
            pcnt += (x2 > bv) ? 1u : 0u;
            pcnt += (x3 > bv) ? 1u : 0u;
            pm[m] = fmaxf(fmaxf(x0, x1), fmaxf(x2, x3));
        }
        float pmax = fmaxf(fmaxf(pm[0], pm[1]), fmaxf(pm[2], pm[3]));

        pmax = fmaxf(pmax, __shfl_xor(pmax, 16, 64));
        pcnt += (unsigned)__shfl_xor((int)pcnt, 16, 64);
        pmax = fmaxf(pmax, __shfl_xor(pmax, 32, 64));
        pcnt += (unsigned)__shfl_xor((int)pcnt, 32, 64);
        if (ks == 0 && kcol < KPD) {
            atomicMax(&gkey[slotbase + kcol], fkey(pmax));
            atomicAdd(&gcnt[slotbase + kcol], pcnt);
        }

#pragma unroll
        for (int kk = 0; kk < 4; ++kk) bfrag[kk] = bnext[kk];
    }
}

// grid: (79 t-chunks, ND, NB), block 256
__global__ __launch_bounds__(256, 3) void mr_main(
    const float* __restrict__ x, const unsigned short* __restrict__ wbf,
    const float* __restrict__ bias, unsigned* __restrict__ gkey,
    unsigned* __restrict__ gcnt)
{
    const int tb = blockIdx.x;
    const int di = blockIdx.y;
    const int b  = blockIdx.z;
    const int d  = 1 << di;
    const int t0 = tb * BM;

    __shared__ __align__(16) unsigned short lA[BM * KPAD];

    const float* xb = x + (size_t)b * CIN * SEQ;
    const unsigned short* wd = wbf + (size_t)di * NKP * KPAD;
    const float* bb = bias + (size_t)di * KPD;
    const size_t slotbase = ((size_t)b * ND + di) * KPD;

    if (t0 + BM <= SEQ)
        mr_body<false>(xb, wd, bb, gkey, gcnt, d, t0, lA, slotbase);
    else
        mr_body<true>(xb, wd, bb, gkey, gcnt, d, t0, lA, slotbase);
}

__global__ __launch_bounds__(256) void mr_fin(
    const unsigned* __restrict__ gkey, const unsigned* __restrict__ gcnt,
    float* __restrict__ out)
{
    const int i = blockIdx.x * 256 + threadIdx.x;   // over NB*ND*KPD
    if (i >= NB * ND * KPD) return;
    const int k  = i % KPD;
    const int di = (i / KPD) % ND;
    const int b  = i / (KPD * ND);
    const float maxv = unfkey(gkey[i]);
    const float ppv  = (float)gcnt[i] * (1.0f / (float)SEQ);
    float* ob = out + (size_t)b * (2 * ND * KPD);
    ob[di * 2 * KPD + k]       = maxv;
    ob[di * 2 * KPD + KPD + k] = ppv;
}

extern "C" void kernel_launch(void* const* d_in, const int* in_sizes, int n_in,
                              void* d_out, int out_size, void* d_ws, size_t ws_size,
                              hipStream_t stream) {
    const float* x    = (const float*)d_in[0];
    const float* w    = (const float*)d_in[1];
    const float* bias = (const float*)d_in[2];
    float* out = (float*)d_out;

    unsigned* gkey = (unsigned*)d_ws;
    unsigned* gcnt = gkey + (size_t)NB * ND * KPD;
    unsigned short* wbf = (unsigned short*)(gcnt + (size_t)NB * ND * KPD);

    hipMemsetAsync(d_ws, 0, (size_t)NB * ND * KPD * 2 * sizeof(unsigned), stream);

    const int wtot = ND * NKP * KPAD;
    wprep<<<(wtot + 255) / 256, 256, 0, stream>>>(w, wbf);

    dim3 grid((SEQ + BM - 1) / BM, ND, NB);
    mr_main<<<grid, 256, 0, stream>>>(x, wbf, bias, gkey, gcnt);

    const int tot = NB * ND * KPD;
    mr_fin<<<(tot + 255) / 256, 256, 0, stream>>>(gkey, gcnt, out);
}